// Round 1
// baseline (245.763 us; speedup 1.0000x reference)
//
#include <hip/hip_runtime.h>

// ExpanderLinearLayer: out[M,N] = input[M,K] @ (W[N,K] * mask[N,K])^T
// M=16384, N=2048, K=2048. fp32 inputs, fp32 output.
//
// Strategy: convert input and masked weight to bf16 (error ~0.03 << 0.112
// threshold), then bf16 MFMA GEMM (m97-structure: 128^2 tile, BK=32,
// global_load_lds width 16, XCD swizzle).

#define MDIM 16384
#define NDIM 2048
#define KDIM 2048
#define BM 128
#define BN 128
#define BK 32
#define GEMM_GRID ((MDIM / BM) * (NDIM / BN))  // 128*16 = 2048

using f32x4   = __attribute__((ext_vector_type(4))) float;
using bf16x8  = __attribute__((ext_vector_type(8))) __bf16;
using ushort8 = __attribute__((ext_vector_type(8))) unsigned short;

__device__ __forceinline__ unsigned short f2bf(float f) {
  unsigned int u = __builtin_bit_cast(unsigned int, f);
  u = u + 0x7FFFu + ((u >> 16) & 1u);  // round-to-nearest-even
  return (unsigned short)(u >> 16);
}

// ---------------- conversion kernels ----------------

__global__ void convert_input_kernel(const float* __restrict__ in,
                                     unsigned short* __restrict__ out) {
  size_t base = ((size_t)blockIdx.x * blockDim.x + threadIdx.x) * 8;
  float4 a = *reinterpret_cast<const float4*>(in + base);
  float4 b = *reinterpret_cast<const float4*>(in + base + 4);
  ushort8 v;
  v[0] = f2bf(a.x); v[1] = f2bf(a.y); v[2] = f2bf(a.z); v[3] = f2bf(a.w);
  v[4] = f2bf(b.x); v[5] = f2bf(b.y); v[6] = f2bf(b.z); v[7] = f2bf(b.w);
  *reinterpret_cast<ushort8*>(out + base) = v;
}

__global__ void convert_weight_kernel(const float* __restrict__ w,
                                      const int* __restrict__ mk,
                                      unsigned short* __restrict__ out) {
  size_t base = ((size_t)blockIdx.x * blockDim.x + threadIdx.x) * 8;
  float4 a = *reinterpret_cast<const float4*>(w + base);
  float4 b = *reinterpret_cast<const float4*>(w + base + 4);
  int4 m0 = *reinterpret_cast<const int4*>(mk + base);
  int4 m1 = *reinterpret_cast<const int4*>(mk + base + 4);
  ushort8 v;
  v[0] = m0.x ? f2bf(a.x) : (unsigned short)0;
  v[1] = m0.y ? f2bf(a.y) : (unsigned short)0;
  v[2] = m0.z ? f2bf(a.z) : (unsigned short)0;
  v[3] = m0.w ? f2bf(a.w) : (unsigned short)0;
  v[4] = m1.x ? f2bf(b.x) : (unsigned short)0;
  v[5] = m1.y ? f2bf(b.y) : (unsigned short)0;
  v[6] = m1.z ? f2bf(b.z) : (unsigned short)0;
  v[7] = m1.w ? f2bf(b.w) : (unsigned short)0;
  *reinterpret_cast<ushort8*>(out + base) = v;
}

// ---------------- GEMM (m97 structure) ----------------
// 256 threads = 4 waves, wave grid 2x2, each wave does 64x64 via 4x4 frags
// of mfma_f32_16x16x32_bf16. LDS: A[128][32], B[128][32] bf16 (linear, for
// global_load_lds). FUSED variant converts fp32->bf16 in the staging step
// (used only if ws_size is too small for the bf16 copies).

template <bool FUSED>
__global__ __launch_bounds__(256) void gemm_bt_kernel(
    const unsigned short* __restrict__ Abf,
    const unsigned short* __restrict__ Bbf,
    const float* __restrict__ Afp,
    const float* __restrict__ Wfp,
    const int* __restrict__ Mk,
    float* __restrict__ C) {
  __shared__ unsigned short As[BM * BK];
  __shared__ unsigned short Bs[BN * BK];

  // XCD-bijective swizzle: grid 2048 = 8 * 256
  int bid = blockIdx.x;
  int wg  = (bid & 7) * (GEMM_GRID / 8) + (bid >> 3);
  int tm  = wg >> 4;  // NDIM/BN == 16
  int tn  = wg & 15;
  int row0 = tm * BM, col0 = tn * BN;

  int t = threadIdx.x;
  int lane = t & 63, wv = t >> 6;
  int wr = wv >> 1, wc = wv & 1;
  int fr = lane & 15, fq = lane >> 4;

  f32x4 acc[4][4];
#pragma unroll
  for (int i = 0; i < 4; ++i)
#pragma unroll
    for (int j = 0; j < 4; ++j) acc[i][j] = f32x4{0.f, 0.f, 0.f, 0.f};

  for (int kt = 0; kt < KDIM; kt += BK) {
    if constexpr (!FUSED) {
#pragma unroll
      for (int j = 0; j < 2; ++j) {
        int c  = j * 256 + t;        // 16B chunk index in tile
        int r  = c >> 2;             // 4 chunks per 64B row
        int ko = (c & 3) * 8;
        __builtin_amdgcn_global_load_lds(
            (const __attribute__((address_space(1))) void*)(Abf + (size_t)(row0 + r) * KDIM + kt + ko),
            (__attribute__((address_space(3))) void*)(As + (size_t)(j * 256 + wv * 64) * 8),
            16, 0, 0);
        __builtin_amdgcn_global_load_lds(
            (const __attribute__((address_space(1))) void*)(Bbf + (size_t)(col0 + r) * KDIM + kt + ko),
            (__attribute__((address_space(3))) void*)(Bs + (size_t)(j * 256 + wv * 64) * 8),
            16, 0, 0);
      }
    } else {
#pragma unroll
      for (int j = 0; j < 2; ++j) {
        int c  = j * 256 + t;
        int r  = c >> 2;
        int ko = (c & 3) * 8;
        const float* ga = Afp + (size_t)(row0 + r) * KDIM + kt + ko;
        float4 a0 = *reinterpret_cast<const float4*>(ga);
        float4 a1 = *reinterpret_cast<const float4*>(ga + 4);
        ushort8 va;
        va[0] = f2bf(a0.x); va[1] = f2bf(a0.y); va[2] = f2bf(a0.z); va[3] = f2bf(a0.w);
        va[4] = f2bf(a1.x); va[5] = f2bf(a1.y); va[6] = f2bf(a1.z); va[7] = f2bf(a1.w);
        *reinterpret_cast<ushort8*>(As + (size_t)c * 8) = va;
        const float* gw = Wfp + (size_t)(col0 + r) * KDIM + kt + ko;
        const int*   gm = Mk  + (size_t)(col0 + r) * KDIM + kt + ko;
        float4 w0 = *reinterpret_cast<const float4*>(gw);
        float4 w1 = *reinterpret_cast<const float4*>(gw + 4);
        int4 m0 = *reinterpret_cast<const int4*>(gm);
        int4 m1 = *reinterpret_cast<const int4*>(gm + 4);
        ushort8 vb;
        vb[0] = m0.x ? f2bf(w0.x) : (unsigned short)0;
        vb[1] = m0.y ? f2bf(w0.y) : (unsigned short)0;
        vb[2] = m0.z ? f2bf(w0.z) : (unsigned short)0;
        vb[3] = m0.w ? f2bf(w0.w) : (unsigned short)0;
        vb[4] = m1.x ? f2bf(w1.x) : (unsigned short)0;
        vb[5] = m1.y ? f2bf(w1.y) : (unsigned short)0;
        vb[6] = m1.z ? f2bf(w1.z) : (unsigned short)0;
        vb[7] = m1.w ? f2bf(w1.w) : (unsigned short)0;
        *reinterpret_cast<ushort8*>(Bs + (size_t)c * 8) = vb;
      }
    }
    __syncthreads();

    bf16x8 af[4], bfr[4];
#pragma unroll
    for (int m2 = 0; m2 < 4; ++m2)
      af[m2] = *reinterpret_cast<const bf16x8*>(As + (wr * 64 + m2 * 16 + fr) * BK + fq * 8);
#pragma unroll
    for (int n2 = 0; n2 < 4; ++n2)
      bfr[n2] = *reinterpret_cast<const bf16x8*>(Bs + (wc * 64 + n2 * 16 + fr) * BK + fq * 8);

#pragma unroll
    for (int m2 = 0; m2 < 4; ++m2)
#pragma unroll
      for (int n2 = 0; n2 < 4; ++n2)
        acc[m2][n2] = __builtin_amdgcn_mfma_f32_16x16x32_bf16(af[m2], bfr[n2], acc[m2][n2], 0, 0, 0);
    __syncthreads();
  }

  // C/D layout (verified m89): col = lane&15, row = (lane>>4)*4 + reg
#pragma unroll
  for (int m2 = 0; m2 < 4; ++m2)
#pragma unroll
    for (int n2 = 0; n2 < 4; ++n2) {
      size_t r0 = (size_t)(row0 + wr * 64 + m2 * 16 + fq * 4);
      size_t c0 = (size_t)(col0 + wc * 64 + n2 * 16 + fr);
#pragma unroll
      for (int i = 0; i < 4; ++i)
        C[(r0 + i) * NDIM + c0] = acc[m2][n2][i];
    }
}

// ---------------- launch ----------------

extern "C" void kernel_launch(void* const* d_in, const int* in_sizes, int n_in,
                              void* d_out, int out_size, void* d_ws, size_t ws_size,
                              hipStream_t stream) {
  const float* input  = (const float*)d_in[0];
  const float* weight = (const float*)d_in[1];
  const int*   mask   = (const int*)d_in[2];
  float* out = (float*)d_out;

  const size_t needA = (size_t)MDIM * KDIM * sizeof(unsigned short);  // 64 MiB
  const size_t needB = (size_t)NDIM * KDIM * sizeof(unsigned short);  // 8 MiB

  if (ws_size >= needA + needB) {
    unsigned short* Abf = (unsigned short*)d_ws;
    unsigned short* Bbf = (unsigned short*)((char*)d_ws + needA);
    convert_input_kernel<<<(MDIM * (size_t)KDIM / 8) / 256, 256, 0, stream>>>(input, Abf);
    convert_weight_kernel<<<(NDIM * (size_t)KDIM / 8) / 256, 256, 0, stream>>>(weight, mask, Bbf);
    gemm_bt_kernel<false><<<GEMM_GRID, 256, 0, stream>>>(Abf, Bbf, nullptr, nullptr, nullptr, out);
  } else {
    gemm_bt_kernel<true><<<GEMM_GRID, 256, 0, stream>>>(nullptr, nullptr, input, weight, mask, out);
  }
}

// Round 2
// 187.533 us; speedup vs baseline: 1.3105x; 1.3105x over previous
//
#include <hip/hip_runtime.h>

// ExpanderLinearLayer: out[M,N] = input[M,K] @ (W[N,K]*mask[N,K])^T
// M=16384, N=2048, K=2048, fp32 in/out.
// bf16 conversion passes + 256x256 8-phase MFMA GEMM (m201 template):
// BK=64, 2 K-tiles/iter, counted vmcnt(4) at phases 4/8, XOR-swizzled LDS,
// raw s_barrier (no vmcnt drain), setprio around MFMA clusters.

#define MDIM 16384
#define NDIM 2048
#define KDIM 2048

#define BM 256
#define BN 256
#define NITER (KDIM / 128)              // 16 iterations, 2 K-tiles of 64 each
#define GRID_X ((MDIM / BM) * (NDIM / BN))  // 64*8 = 512

using f32x4   = __attribute__((ext_vector_type(4))) float;
using bf16x8  = __attribute__((ext_vector_type(8))) __bf16;
using ushort8 = __attribute__((ext_vector_type(8))) unsigned short;

__device__ __forceinline__ unsigned short f2bf(float f) {
  unsigned int u = __builtin_bit_cast(unsigned int, f);
  u = u + 0x7FFFu + ((u >> 16) & 1u);  // RNE
  return (unsigned short)(u >> 16);
}

// ---------------- conversion kernels ----------------

__global__ void convert_input_kernel(const float* __restrict__ in,
                                     unsigned short* __restrict__ out) {
  size_t base = ((size_t)blockIdx.x * blockDim.x + threadIdx.x) * 8;
  float4 a = *reinterpret_cast<const float4*>(in + base);
  float4 b = *reinterpret_cast<const float4*>(in + base + 4);
  ushort8 v;
  v[0] = f2bf(a.x); v[1] = f2bf(a.y); v[2] = f2bf(a.z); v[3] = f2bf(a.w);
  v[4] = f2bf(b.x); v[5] = f2bf(b.y); v[6] = f2bf(b.z); v[7] = f2bf(b.w);
  *reinterpret_cast<ushort8*>(out + base) = v;
}

__global__ void convert_weight_kernel(const float* __restrict__ w,
                                      const int* __restrict__ mk,
                                      unsigned short* __restrict__ out) {
  size_t base = ((size_t)blockIdx.x * blockDim.x + threadIdx.x) * 8;
  float4 a = *reinterpret_cast<const float4*>(w + base);
  float4 b = *reinterpret_cast<const float4*>(w + base + 4);
  int4 m0 = *reinterpret_cast<const int4*>(mk + base);
  int4 m1 = *reinterpret_cast<const int4*>(mk + base + 4);
  ushort8 v;
  v[0] = m0.x ? f2bf(a.x) : (unsigned short)0;
  v[1] = m0.y ? f2bf(a.y) : (unsigned short)0;
  v[2] = m0.z ? f2bf(a.z) : (unsigned short)0;
  v[3] = m0.w ? f2bf(a.w) : (unsigned short)0;
  v[4] = m1.x ? f2bf(b.x) : (unsigned short)0;
  v[5] = m1.y ? f2bf(b.y) : (unsigned short)0;
  v[6] = m1.z ? f2bf(b.z) : (unsigned short)0;
  v[7] = m1.w ? f2bf(b.w) : (unsigned short)0;
  *reinterpret_cast<ushort8*>(out + base) = v;
}

// ---------------- 8-phase GEMM ----------------

__device__ __forceinline__ f32x4 MF(bf16x8 a, bf16x8 b, f32x4 c) {
  return __builtin_amdgcn_mfma_f32_16x16x32_bf16(a, b, c, 0, 0, 0);
}
__device__ __forceinline__ void bar() {
  asm volatile("" ::: "memory");
  __builtin_amdgcn_s_barrier();
  asm volatile("" ::: "memory");
}
#define VMCNT(n) asm volatile("s_waitcnt vmcnt(" #n ")" ::: "memory")

// LDS: per operand 4 slots [buf(2)][khalf(2)] of 256 rows x 32 k bf16 (16 KiB).
// 16-B chunk swizzle within a row: chunk' = chunk ^ (row & 3), applied on the
// pre-swizzled global SOURCE of global_load_lds (linear dest) and on ds_read.
__global__ __launch_bounds__(512, 2) void gemm8p(
    const unsigned short* __restrict__ Abf,
    const unsigned short* __restrict__ Bbf,
    float* __restrict__ C) {
  __shared__ __attribute__((aligned(16))) unsigned short Asl[4 * 8192];
  __shared__ __attribute__((aligned(16))) unsigned short Bsl[4 * 8192];

  // bijective XCD swizzle (512 % 8 == 0)
  int bid = blockIdx.x;
  int wgs = (bid & 7) * (GRID_X / 8) + (bid >> 3);
  int tm = wgs >> 3;  // NDIM/BN == 8
  int tn = wgs & 7;
  int row0 = tm * BM, col0 = tn * BN;

  int t = threadIdx.x;
  int lane = t & 63, wid = t >> 6;
  int wr = wid >> 2, wc = wid & 3;       // 2 x 4 wave grid
  int fr = lane & 15, fq = lane >> 4;

  // staging: thread handles LDS 16B-chunks p0,p1 of each slot (1024 chunks)
  int p0 = (wid * 2 + 0) * 64 + lane;
  int p1 = (wid * 2 + 1) * 64 + lane;
  int r0 = p0 >> 2, kc0 = ((p0 & 3) ^ (r0 & 3)) * 8;  // inverse-swizzled src
  int r1 = p1 >> 2, kc1 = ((p1 & 3) ^ (r1 & 3)) * 8;
  size_t offA0 = (size_t)(row0 + r0) * KDIM + kc0;
  size_t offA1 = (size_t)(row0 + r1) * KDIM + kc1;
  size_t offB0 = (size_t)(col0 + r0) * KDIM + kc0;
  size_t offB1 = (size_t)(col0 + r1) * KDIM + kc1;
  int ldsw0 = (wid * 2 + 0) * 512;  // elements; wave-uniform
  int ldsw1 = (wid * 2 + 1) * 512;

  // frag ds_read offsets (swizzled chunk)
  int kxor = (fq ^ (fr & 3)) * 8;
  int aoff = (wr * 128 + fr) * 32 + kxor;
  int boff = (wc * 64 + fr) * 32 + kxor;

  f32x4 acc[8][4];
#pragma unroll
  for (int m = 0; m < 8; ++m)
#pragma unroll
    for (int n = 0; n < 4; ++n) acc[m][n] = f32x4{0.f, 0.f, 0.f, 0.f};
  bf16x8 afr[8];

#define SLOT_A(b, kh) (Asl + ((b) * 2 + (kh)) * 8192)
#define SLOT_B(b, kh) (Bsl + ((b) * 2 + (kh)) * 8192)

#define STG(slot, base, o0, o1, ke) do {                                        \
  __builtin_amdgcn_global_load_lds(                                             \
      (const __attribute__((address_space(1))) void*)((base) + (o0) + (ke)),    \
      (__attribute__((address_space(3))) void*)((slot) + ldsw0), 16, 0, 0);     \
  __builtin_amdgcn_global_load_lds(                                             \
      (const __attribute__((address_space(1))) void*)((base) + (o1) + (ke)),    \
      (__attribute__((address_space(3))) void*)((slot) + ldsw1), 16, 0, 0);     \
} while (0)

// phase (buf b, k-half kh, n-half nh): A frags loaded on nh==0, reused nh==1.
#define PHASE(b, kh, nh, STAGES, WAITS) do {                                    \
  if ((nh) == 0) {                                                              \
    const unsigned short* _ap = SLOT_A(b, kh) + aoff;                           \
    _Pragma("unroll")                                                           \
    for (int _m = 0; _m < 8; ++_m) afr[_m] = *(const bf16x8*)(_ap + _m * 512);  \
  }                                                                             \
  const unsigned short* _bp = SLOT_B(b, kh) + boff + (nh) * 1024;               \
  bf16x8 _b0 = *(const bf16x8*)(_bp);                                           \
  bf16x8 _b1 = *(const bf16x8*)(_bp + 512);                                     \
  STAGES;                                                                       \
  WAITS;                                                                        \
  bar();                                                                        \
  __builtin_amdgcn_s_setprio(1);                                                \
  _Pragma("unroll")                                                             \
  for (int _m = 0; _m < 8; ++_m) {                                              \
    acc[_m][(nh) * 2]     = MF(afr[_m], _b0, acc[_m][(nh) * 2]);                \
    acc[_m][(nh) * 2 + 1] = MF(afr[_m], _b1, acc[_m][(nh) * 2 + 1]);            \
  }                                                                             \
  __builtin_amdgcn_s_setprio(0);                                                \
  bar();                                                                        \
} while (0)

  // prologue: tile0 (buf0) fully + tile1 (buf1) k0; wait tile0, keep 4 in flight
  STG(SLOT_A(0, 0), Abf, offA0, offA1, 0);
  STG(SLOT_B(0, 0), Bbf, offB0, offB1, 0);
  STG(SLOT_A(0, 1), Abf, offA0, offA1, 32);
  STG(SLOT_B(0, 1), Bbf, offB0, offB1, 32);
  STG(SLOT_A(1, 0), Abf, offA0, offA1, 64);
  STG(SLOT_B(1, 0), Bbf, offB0, offB1, 64);
  VMCNT(4);
  bar();

  for (int i = 0; i < NITER - 1; ++i) {
    int kb = i * 128;
    // phases 1-4: tile 2i (buf0); phases 5-8: tile 2i+1 (buf1)
    PHASE(0, 0, 0, { STG(SLOT_A(1, 1), Abf, offA0, offA1, kb + 96);
                     STG(SLOT_B(1, 1), Bbf, offB0, offB1, kb + 96); }, );
    PHASE(0, 0, 1, , );
    PHASE(0, 1, 0, STG(SLOT_A(0, 0), Abf, offA0, offA1, kb + 128), );
    PHASE(0, 1, 1, STG(SLOT_B(0, 0), Bbf, offB0, offB1, kb + 128), VMCNT(4));
    PHASE(1, 0, 0, { STG(SLOT_A(0, 1), Abf, offA0, offA1, kb + 160);
                     STG(SLOT_B(0, 1), Bbf, offB0, offB1, kb + 160); }, );
    PHASE(1, 0, 1, , );
    PHASE(1, 1, 0, STG(SLOT_A(1, 0), Abf, offA0, offA1, kb + 192), );
    PHASE(1, 1, 1, STG(SLOT_B(1, 0), Bbf, offB0, offB1, kb + 192), VMCNT(4));
  }
  {  // last iteration: only tile 2i+1's k1 still needs staging
    int kb = (NITER - 1) * 128;
    PHASE(0, 0, 0, { STG(SLOT_A(1, 1), Abf, offA0, offA1, kb + 96);
                     STG(SLOT_B(1, 1), Bbf, offB0, offB1, kb + 96); }, );
    PHASE(0, 0, 1, , );
    PHASE(0, 1, 0, , );
    PHASE(0, 1, 1, , VMCNT(0));
    PHASE(1, 0, 0, , );
    PHASE(1, 0, 1, , );
    PHASE(1, 1, 0, , );
    PHASE(1, 1, 1, , );
  }

  // epilogue: C/D layout col=lane&15, row=(lane>>4)*4+reg
  size_t crow = (size_t)(row0 + wr * 128 + fq * 4);
  int ccol = col0 + wc * 64 + fr;
#pragma unroll
  for (int m = 0; m < 8; ++m)
#pragma unroll
    for (int n = 0; n < 4; ++n) {
      float* cp = C + (crow + m * 16) * NDIM + ccol + n * 16;
#pragma unroll
      for (int e = 0; e < 4; ++e) cp[(size_t)e * NDIM] = acc[m][n][e];
    }
#undef PHASE
#undef STG
#undef SLOT_A
#undef SLOT_B
}

// ---------------- fallback (fused conversion, 128^2 m97-structure) ----------

__global__ __launch_bounds__(256) void gemm_fused_fallback(
    const float* __restrict__ Afp,
    const float* __restrict__ Wfp,
    const int* __restrict__ Mk,
    float* __restrict__ C) {
  __shared__ unsigned short As[128 * 32];
  __shared__ unsigned short Bs[128 * 32];
  int bid = blockIdx.x;
  int nwg = (MDIM / 128) * (NDIM / 128);
  int wg = (bid & 7) * (nwg / 8) + (bid >> 3);
  int tm = wg >> 4, tn = wg & 15;
  int row0 = tm * 128, col0 = tn * 128;
  int t = threadIdx.x;
  int lane = t & 63, wv = t >> 6;
  int wr = wv >> 1, wc = wv & 1;
  int fr = lane & 15, fq = lane >> 4;
  f32x4 acc[4][4];
#pragma unroll
  for (int i = 0; i < 4; ++i)
#pragma unroll
    for (int j = 0; j < 4; ++j) acc[i][j] = f32x4{0.f, 0.f, 0.f, 0.f};
  for (int kt = 0; kt < KDIM; kt += 32) {
#pragma unroll
    for (int j = 0; j < 2; ++j) {
      int c = j * 256 + t;
      int r = c >> 2;
      int ko = (c & 3) * 8;
      const float* ga = Afp + (size_t)(row0 + r) * KDIM + kt + ko;
      float4 a0 = *reinterpret_cast<const float4*>(ga);
      float4 a1 = *reinterpret_cast<const float4*>(ga + 4);
      ushort8 va;
      va[0] = f2bf(a0.x); va[1] = f2bf(a0.y); va[2] = f2bf(a0.z); va[3] = f2bf(a0.w);
      va[4] = f2bf(a1.x); va[5] = f2bf(a1.y); va[6] = f2bf(a1.z); va[7] = f2bf(a1.w);
      *reinterpret_cast<ushort8*>(As + (size_t)c * 8) = va;
      const float* gw = Wfp + (size_t)(col0 + r) * KDIM + kt + ko;
      const int* gm = Mk + (size_t)(col0 + r) * KDIM + kt + ko;
      float4 w0 = *reinterpret_cast<const float4*>(gw);
      float4 w1 = *reinterpret_cast<const float4*>(gw + 4);
      int4 m0 = *reinterpret_cast<const int4*>(gm);
      int4 m1 = *reinterpret_cast<const int4*>(gm + 4);
      ushort8 vb;
      vb[0] = m0.x ? f2bf(w0.x) : (unsigned short)0;
      vb[1] = m0.y ? f2bf(w0.y) : (unsigned short)0;
      vb[2] = m0.z ? f2bf(w0.z) : (unsigned short)0;
      vb[3] = m0.w ? f2bf(w0.w) : (unsigned short)0;
      vb[4] = m1.x ? f2bf(w1.x) : (unsigned short)0;
      vb[5] = m1.y ? f2bf(w1.y) : (unsigned short)0;
      vb[6] = m1.z ? f2bf(w1.z) : (unsigned short)0;
      vb[7] = m1.w ? f2bf(w1.w) : (unsigned short)0;
      *reinterpret_cast<ushort8*>(Bs + (size_t)c * 8) = vb;
    }
    __syncthreads();
    bf16x8 af[4], bfr[4];
#pragma unroll
    for (int m2 = 0; m2 < 4; ++m2)
      af[m2] = *reinterpret_cast<const bf16x8*>(As + (wr * 64 + m2 * 16 + fr) * 32 + fq * 8);
#pragma unroll
    for (int n2 = 0; n2 < 4; ++n2)
      bfr[n2] = *reinterpret_cast<const bf16x8*>(Bs + (wc * 64 + n2 * 16 + fr) * 32 + fq * 8);
#pragma unroll
    for (int m2 = 0; m2 < 4; ++m2)
#pragma unroll
      for (int n2 = 0; n2 < 4; ++n2)
        acc[m2][n2] = MF(af[m2], bfr[n2], acc[m2][n2]);
    __syncthreads();
  }
#pragma unroll
  for (int m2 = 0; m2 < 4; ++m2)
#pragma unroll
    for (int n2 = 0; n2 < 4; ++n2) {
      size_t r0 = (size_t)(row0 + wr * 64 + m2 * 16 + fq * 4);
      size_t c0 = (size_t)(col0 + wc * 64 + n2 * 16 + fr);
#pragma unroll
      for (int i = 0; i < 4; ++i) C[(r0 + i) * NDIM + c0] = acc[m2][n2][i];
    }
}

// ---------------- launch ----------------

extern "C" void kernel_launch(void* const* d_in, const int* in_sizes, int n_in,
                              void* d_out, int out_size, void* d_ws, size_t ws_size,
                              hipStream_t stream) {
  const float* input  = (const float*)d_in[0];
  const float* weight = (const float*)d_in[1];
  const int*   mask   = (const int*)d_in[2];
  float* out = (float*)d_out;

  const size_t needA = (size_t)MDIM * KDIM * sizeof(unsigned short);
  const size_t needB = (size_t)NDIM * KDIM * sizeof(unsigned short);

  if (ws_size >= needA + needB) {
    unsigned short* Abf = (unsigned short*)d_ws;
    unsigned short* Bbf = (unsigned short*)((char*)d_ws + needA);
    convert_input_kernel<<<(MDIM * (size_t)KDIM / 8) / 256, 256, 0, stream>>>(input, Abf);
    convert_weight_kernel<<<(NDIM * (size_t)KDIM / 8) / 256, 256, 0, stream>>>(weight, mask, Bbf);
    gemm8p<<<GRID_X, 512, 0, stream>>>(Abf, Bbf, out);
  } else {
    int nwg = (MDIM / 128) * (NDIM / 128);
    gemm_fused_fallback<<<nwg, 256, 0, stream>>>(input, weight, mask, out);
  }
}

// Round 3
// 180.374 us; speedup vs baseline: 1.3625x; 1.0397x over previous
//
#include <hip/hip_runtime.h>

// ExpanderLinearLayer: out[M,N] = input[M,K] @ (W[N,K]*mask[N,K])^T
// M=16384, N=2048, K=2048, fp32 in/out.
// bf16 conversion passes + 256x256 8-phase MFMA GEMM (m201 template):
// BK=64, 2 K-tiles/iter, counted vmcnt(4) at phases 4/8, XOR-swizzled LDS
// (chunk ^= (row>>1)&3 -- 8-row period, see R3 notes), raw s_barrier,
// setprio around MFMA clusters.

#define MDIM 16384
#define NDIM 2048
#define KDIM 2048

#define BM 256
#define BN 256
#define NITER (KDIM / 128)              // 16 iterations, 2 K-tiles of 64 each
#define GRID_X ((MDIM / BM) * (NDIM / BN))  // 64*8 = 512

using f32x4   = __attribute__((ext_vector_type(4))) float;
using bf16x8  = __attribute__((ext_vector_type(8))) __bf16;
using ushort8 = __attribute__((ext_vector_type(8))) unsigned short;

__device__ __forceinline__ unsigned short f2bf(float f) {
  unsigned int u = __builtin_bit_cast(unsigned int, f);
  u = u + 0x7FFFu + ((u >> 16) & 1u);  // RNE
  return (unsigned short)(u >> 16);
}

// ---------------- conversion kernels ----------------

__global__ void convert_input_kernel(const float* __restrict__ in,
                                     unsigned short* __restrict__ out) {
  size_t base = ((size_t)blockIdx.x * blockDim.x + threadIdx.x) * 8;
  float4 a = *reinterpret_cast<const float4*>(in + base);
  float4 b = *reinterpret_cast<const float4*>(in + base + 4);
  ushort8 v;
  v[0] = f2bf(a.x); v[1] = f2bf(a.y); v[2] = f2bf(a.z); v[3] = f2bf(a.w);
  v[4] = f2bf(b.x); v[5] = f2bf(b.y); v[6] = f2bf(b.z); v[7] = f2bf(b.w);
  *reinterpret_cast<ushort8*>(out + base) = v;
}

__global__ void convert_weight_kernel(const float* __restrict__ w,
                                      const int* __restrict__ mk,
                                      unsigned short* __restrict__ out) {
  size_t base = ((size_t)blockIdx.x * blockDim.x + threadIdx.x) * 8;
  float4 a = *reinterpret_cast<const float4*>(w + base);
  float4 b = *reinterpret_cast<const float4*>(w + base + 4);
  int4 m0 = *reinterpret_cast<const int4*>(mk + base);
  int4 m1 = *reinterpret_cast<const int4*>(mk + base + 4);
  ushort8 v;
  v[0] = m0.x ? f2bf(a.x) : (unsigned short)0;
  v[1] = m0.y ? f2bf(a.y) : (unsigned short)0;
  v[2] = m0.z ? f2bf(a.z) : (unsigned short)0;
  v[3] = m0.w ? f2bf(a.w) : (unsigned short)0;
  v[4] = m1.x ? f2bf(b.x) : (unsigned short)0;
  v[5] = m1.y ? f2bf(b.y) : (unsigned short)0;
  v[6] = m1.z ? f2bf(b.z) : (unsigned short)0;
  v[7] = m1.w ? f2bf(b.w) : (unsigned short)0;
  *reinterpret_cast<ushort8*>(out + base) = v;
}

// ---------------- 8-phase GEMM ----------------

__device__ __forceinline__ f32x4 MF(bf16x8 a, bf16x8 b, f32x4 c) {
  return __builtin_amdgcn_mfma_f32_16x16x32_bf16(a, b, c, 0, 0, 0);
}
__device__ __forceinline__ void bar() {
  asm volatile("" ::: "memory");
  __builtin_amdgcn_s_barrier();
  asm volatile("" ::: "memory");
}
#define VMCNT(n) asm volatile("s_waitcnt vmcnt(" #n ")" ::: "memory")

// LDS: per operand 4 slots [buf(2)][khalf(2)] of 256 rows x 32 k bf16 (16 KiB).
// Swizzle: 16-B chunk within a 64-B row, chunk' = chunk ^ ((row>>1)&3).
// 8-row period: within an 8-lane LDS service group, even rows spread over
// banks 0-15 and odd rows over 16-31 with distinct chunks -> conflict-free.
// Applied on the pre-swizzled global SOURCE (gload_lds dest stays linear,
// rule #21) and identically on the ds_read address.
__global__ __launch_bounds__(512, 2) void gemm8p(
    const unsigned short* __restrict__ Abf,
    const unsigned short* __restrict__ Bbf,
    float* __restrict__ C) {
  __shared__ __attribute__((aligned(16))) unsigned short Asl[4 * 8192];
  __shared__ __attribute__((aligned(16))) unsigned short Bsl[4 * 8192];

  // bijective XCD swizzle (512 % 8 == 0)
  int bid = blockIdx.x;
  int wgs = (bid & 7) * (GRID_X / 8) + (bid >> 3);
  int tm = wgs >> 3;  // NDIM/BN == 8
  int tn = wgs & 7;
  int row0 = tm * BM, col0 = tn * BN;

  int t = threadIdx.x;
  int lane = t & 63, wid = t >> 6;
  int wr = wid >> 2, wc = wid & 3;       // 2 x 4 wave grid
  int fr = lane & 15, fq = lane >> 4;

  // staging: thread handles LDS 16B-chunks p0,p1 of each slot (1024 chunks)
  int p0 = (wid * 2 + 0) * 64 + lane;
  int p1 = (wid * 2 + 1) * 64 + lane;
  int r0 = p0 >> 2, kc0 = ((p0 & 3) ^ ((r0 >> 1) & 3)) * 8;  // inverse-swz src
  int r1 = p1 >> 2, kc1 = ((p1 & 3) ^ ((r1 >> 1) & 3)) * 8;
  size_t offA0 = (size_t)(row0 + r0) * KDIM + kc0;
  size_t offA1 = (size_t)(row0 + r1) * KDIM + kc1;
  size_t offB0 = (size_t)(col0 + r0) * KDIM + kc0;
  size_t offB1 = (size_t)(col0 + r1) * KDIM + kc1;
  int ldsw0 = (wid * 2 + 0) * 512;  // elements; wave-uniform
  int ldsw1 = (wid * 2 + 1) * 512;

  // frag ds_read offsets. Row key (row>>1)&3 is invariant under +16m / wave
  // offsets (all multiples of 16), so one kxor per lane covers all frags.
  int kxor = (fq ^ ((fr >> 1) & 3)) * 8;
  int aoff = (wr * 128 + fr) * 32 + kxor;
  int boff = (wc * 64 + fr) * 32 + kxor;

  f32x4 acc[8][4];
#pragma unroll
  for (int m = 0; m < 8; ++m)
#pragma unroll
    for (int n = 0; n < 4; ++n) acc[m][n] = f32x4{0.f, 0.f, 0.f, 0.f};
  bf16x8 afr[8];

#define SLOT_A(b, kh) (Asl + ((b) * 2 + (kh)) * 8192)
#define SLOT_B(b, kh) (Bsl + ((b) * 2 + (kh)) * 8192)

#define STG(slot, base, o0, o1, ke) do {                                        \
  __builtin_amdgcn_global_load_lds(                                             \
      (const __attribute__((address_space(1))) void*)((base) + (o0) + (ke)),    \
      (__attribute__((address_space(3))) void*)((slot) + ldsw0), 16, 0, 0);     \
  __builtin_amdgcn_global_load_lds(                                             \
      (const __attribute__((address_space(1))) void*)((base) + (o1) + (ke)),    \
      (__attribute__((address_space(3))) void*)((slot) + ldsw1), 16, 0, 0);     \
} while (0)

// phase (buf b, k-half kh, n-half nh): A frags loaded on nh==0, reused nh==1.
#define PHASE(b, kh, nh, STAGES, WAITS) do {                                    \
  if ((nh) == 0) {                                                              \
    const unsigned short* _ap = SLOT_A(b, kh) + aoff;                           \
    _Pragma("unroll")                                                           \
    for (int _m = 0; _m < 8; ++_m) afr[_m] = *(const bf16x8*)(_ap + _m * 512);  \
  }                                                                             \
  const unsigned short* _bp = SLOT_B(b, kh) + boff + (nh) * 1024;               \
  bf16x8 _b0 = *(const bf16x8*)(_bp);                                           \
  bf16x8 _b1 = *(const bf16x8*)(_bp + 512);                                     \
  STAGES;                                                                       \
  WAITS;                                                                        \
  bar();                                                                        \
  __builtin_amdgcn_s_setprio(1);                                                \
  _Pragma("unroll")                                                             \
  for (int _m = 0; _m < 8; ++_m) {                                              \
    acc[_m][(nh) * 2]     = MF(afr[_m], _b0, acc[_m][(nh) * 2]);                \
    acc[_m][(nh) * 2 + 1] = MF(afr[_m], _b1, acc[_m][(nh) * 2 + 1]);            \
  }                                                                             \
  __builtin_amdgcn_s_setprio(0);                                                \
  bar();                                                                        \
} while (0)

  // prologue: tile0 (buf0) fully + tile1 (buf1) k0; wait tile0, keep 4 in flight
  STG(SLOT_A(0, 0), Abf, offA0, offA1, 0);
  STG(SLOT_B(0, 0), Bbf, offB0, offB1, 0);
  STG(SLOT_A(0, 1), Abf, offA0, offA1, 32);
  STG(SLOT_B(0, 1), Bbf, offB0, offB1, 32);
  STG(SLOT_A(1, 0), Abf, offA0, offA1, 64);
  STG(SLOT_B(1, 0), Bbf, offB0, offB1, 64);
  VMCNT(4);
  bar();

  for (int i = 0; i < NITER - 1; ++i) {
    int kb = i * 128;
    // phases 1-4: tile 2i (buf0); phases 5-8: tile 2i+1 (buf1)
    PHASE(0, 0, 0, { STG(SLOT_A(1, 1), Abf, offA0, offA1, kb + 96);
                     STG(SLOT_B(1, 1), Bbf, offB0, offB1, kb + 96); }, );
    PHASE(0, 0, 1, , );
    PHASE(0, 1, 0, STG(SLOT_A(0, 0), Abf, offA0, offA1, kb + 128), );
    PHASE(0, 1, 1, STG(SLOT_B(0, 0), Bbf, offB0, offB1, kb + 128), VMCNT(4));
    PHASE(1, 0, 0, { STG(SLOT_A(0, 1), Abf, offA0, offA1, kb + 160);
                     STG(SLOT_B(0, 1), Bbf, offB0, offB1, kb + 160); }, );
    PHASE(1, 0, 1, , );
    PHASE(1, 1, 0, STG(SLOT_A(1, 0), Abf, offA0, offA1, kb + 192), );
    PHASE(1, 1, 1, STG(SLOT_B(1, 0), Bbf, offB0, offB1, kb + 192), VMCNT(4));
  }
  {  // last iteration: only tile 2i+1's k1 still needs staging
    int kb = (NITER - 1) * 128;
    PHASE(0, 0, 0, { STG(SLOT_A(1, 1), Abf, offA0, offA1, kb + 96);
                     STG(SLOT_B(1, 1), Bbf, offB0, offB1, kb + 96); }, );
    PHASE(0, 0, 1, , );
    PHASE(0, 1, 0, , );
    PHASE(0, 1, 1, , VMCNT(0));
    PHASE(1, 0, 0, , );
    PHASE(1, 0, 1, , );
    PHASE(1, 1, 0, , );
    PHASE(1, 1, 1, , );
  }

  // epilogue: C/D layout col=lane&15, row=(lane>>4)*4+reg
  size_t crow = (size_t)(row0 + wr * 128 + fq * 4);
  int ccol = col0 + wc * 64 + fr;
#pragma unroll
  for (int m = 0; m < 8; ++m)
#pragma unroll
    for (int n = 0; n < 4; ++n) {
      float* cp = C + (crow + m * 16) * NDIM + ccol + n * 16;
#pragma unroll
      for (int e = 0; e < 4; ++e) cp[(size_t)e * NDIM] = acc[m][n][e];
    }
#undef PHASE
#undef STG
#undef SLOT_A
#undef SLOT_B
}

// ---------------- fallback (fused conversion, 128^2 m97-structure) ----------

__global__ __launch_bounds__(256) void gemm_fused_fallback(
    const float* __restrict__ Afp,
    const float* __restrict__ Wfp,
    const int* __restrict__ Mk,
    float* __restrict__ C) {
  __shared__ unsigned short As[128 * 32];
  __shared__ unsigned short Bs[128 * 32];
  int bid = blockIdx.x;
  int nwg = (MDIM / 128) * (NDIM / 128);
  int wg = (bid & 7) * (nwg / 8) + (bid >> 3);
  int tm = wg >> 4, tn = wg & 15;
  int row0 = tm * 128, col0 = tn * 128;
  int t = threadIdx.x;
  int lane = t & 63, wv = t >> 6;
  int wr = wv >> 1, wc = wv & 1;
  int fr = lane & 15, fq = lane >> 4;
  f32x4 acc[4][4];
#pragma unroll
  for (int i = 0; i < 4; ++i)
#pragma unroll
    for (int j = 0; j < 4; ++j) acc[i][j] = f32x4{0.f, 0.f, 0.f, 0.f};
  for (int kt = 0; kt < KDIM; kt += 32) {
#pragma unroll
    for (int j = 0; j < 2; ++j) {
      int c = j * 256 + t;
      int r = c >> 2;
      int ko = (c & 3) * 8;
      const float* ga = Afp + (size_t)(row0 + r) * KDIM + kt + ko;
      float4 a0 = *reinterpret_cast<const float4*>(ga);
      float4 a1 = *reinterpret_cast<const float4*>(ga + 4);
      ushort8 va;
      va[0] = f2bf(a0.x); va[1] = f2bf(a0.y); va[2] = f2bf(a0.z); va[3] = f2bf(a0.w);
      va[4] = f2bf(a1.x); va[5] = f2bf(a1.y); va[6] = f2bf(a1.z); va[7] = f2bf(a1.w);
      *reinterpret_cast<ushort8*>(As + (size_t)c * 8) = va;
      const float* gw = Wfp + (size_t)(col0 + r) * KDIM + kt + ko;
      const int* gm = Mk + (size_t)(col0 + r) * KDIM + kt + ko;
      float4 w0 = *reinterpret_cast<const float4*>(gw);
      float4 w1 = *reinterpret_cast<const float4*>(gw + 4);
      int4 m0 = *reinterpret_cast<const int4*>(gm);
      int4 m1 = *reinterpret_cast<const int4*>(gm + 4);
      ushort8 vb;
      vb[0] = m0.x ? f2bf(w0.x) : (unsigned short)0;
      vb[1] = m0.y ? f2bf(w0.y) : (unsigned short)0;
      vb[2] = m0.z ? f2bf(w0.z) : (unsigned short)0;
      vb[3] = m0.w ? f2bf(w0.w) : (unsigned short)0;
      vb[4] = m1.x ? f2bf(w1.x) : (unsigned short)0;
      vb[5] = m1.y ? f2bf(w1.y) : (unsigned short)0;
      vb[6] = m1.z ? f2bf(w1.z) : (unsigned short)0;
      vb[7] = m1.w ? f2bf(w1.w) : (unsigned short)0;
      *reinterpret_cast<ushort8*>(Bs + (size_t)c * 8) = vb;
    }
    __syncthreads();
    bf16x8 af[4], bfr[4];
#pragma unroll
    for (int m2 = 0; m2 < 4; ++m2)
      af[m2] = *reinterpret_cast<const bf16x8*>(As + (wr * 64 + m2 * 16 + fr) * 32 + fq * 8);
#pragma unroll
    for (int n2 = 0; n2 < 4; ++n2)
      bfr[n2] = *reinterpret_cast<const bf16x8*>(Bs + (wc * 64 + n2 * 16 + fr) * 32 + fq * 8);
#pragma unroll
    for (int m2 = 0; m2 < 4; ++m2)
#pragma unroll
      for (int n2 = 0; n2 < 4; ++n2)
        acc[m2][n2] = MF(af[m2], bfr[n2], acc[m2][n2]);
    __syncthreads();
  }
#pragma unroll
  for (int m2 = 0; m2 < 4; ++m2)
#pragma unroll
    for (int n2 = 0; n2 < 4; ++n2) {
      size_t r0 = (size_t)(row0 + wr * 64 + m2 * 16 + fq * 4);
      size_t c0 = (size_t)(col0 + wc * 64 + n2 * 16 + fr);
#pragma unroll
      for (int i = 0; i < 4; ++i) C[(r0 + i) * NDIM + c0] = acc[m2][n2][i];
    }
}

// ---------------- launch ----------------

extern "C" void kernel_launch(void* const* d_in, const int* in_sizes, int n_in,
                              void* d_out, int out_size, void* d_ws, size_t ws_size,
                              hipStream_t stream) {
  const float* input  = (const float*)d_in[0];
  const float* weight = (const float*)d_in[1];
  const int*   mask   = (const int*)d_in[2];
  float* out = (float*)d_out;

  const size_t needA = (size_t)MDIM * KDIM * sizeof(unsigned short);
  const size_t needB = (size_t)NDIM * KDIM * sizeof(unsigned short);

  if (ws_size >= needA + needB) {
    unsigned short* Abf = (unsigned short*)d_ws;
    unsigned short* Bbf = (unsigned short*)((char*)d_ws + needA);
    convert_input_kernel<<<(MDIM * (size_t)KDIM / 8) / 256, 256, 0, stream>>>(input, Abf);
    convert_weight_kernel<<<(NDIM * (size_t)KDIM / 8) / 256, 256, 0, stream>>>(weight, mask, Bbf);
    gemm8p<<<GRID_X, 512, 0, stream>>>(Abf, Bbf, out);
  } else {
    int nwg = (MDIM / 128) * (NDIM / 128);
    gemm_fused_fallback<<<nwg, 256, 0, stream>>>(input, weight, mask, out);
  }
}